// Round 13
// baseline (601.184 us; speedup 1.0000x reference)
//
#include <hip/hip_runtime.h>
#include <cstdint>

#define EPS 1e-5
typedef unsigned long long u64;
typedef unsigned int u32;

struct BnArgs { const float *g[6], *b[6], *m[6], *v[6]; };
struct PackArgs { const float* w[5]; u64* wbt[5]; };

// ---------------------------------------------------------------------------
// Fused BN prep: offsets {0,128,256,512,768,1280}, total 1792.
// ---------------------------------------------------------------------------
__global__ void bn_prep_all(BnArgs p, double* __restrict__ scale_all,
                            double* __restrict__ shift_all) {
    int i = blockIdx.x * 256 + threadIdx.x;
    if (i >= 1792) return;
    int l, base;
    if (i < 128)       { l = 0; base = 0; }
    else if (i < 256)  { l = 1; base = 128; }
    else if (i < 512)  { l = 2; base = 256; }
    else if (i < 768)  { l = 3; base = 512; }
    else if (i < 1280) { l = 4; base = 768; }
    else               { l = 5; base = 1280; }
    const int c = i - base;
    double inv = (double)p.g[l][c] / sqrt((double)p.v[l][c] + EPS);
    scale_all[i] = inv;
    shift_all[i] = (double)p.b[l][c] - (double)p.m[l][c] * inv;
}

__global__ void zero_out(float* __restrict__ out, int n) {
    int i = blockIdx.x * blockDim.x + threadIdx.x;
    if (i < n) out[i] = 0.f;
}

// grid-stride u64 zero (borders of padded bit tensors)
__global__ void zero_u64(u64* __restrict__ p, size_t n) {
    size_t i = (size_t)blockIdx.x * 256 + threadIdx.x;
    const size_t step = (size_t)gridDim.x * 256;
    for (; i < n; i += step) p[i] = 0ull;
}

// ---------------------------------------------------------------------------
// Fused weight pack, tap-major: wbt[(tap*OTOT + o)*W64 + w]. A = alpha*scale.
// ---------------------------------------------------------------------------
__global__ void pack_all(PackArgs pk, const double* __restrict__ scale_all,
                         double* __restrict__ A_all) {
    const int ob = blockIdx.x;
    const int t = threadIdx.x;
    int l, base, Cin, bnoff, OTOT;
    if (ob < 128)       { l = 0; base = 0;    Cin = 128; bnoff = 128;  OTOT = 128; }
    else if (ob < 384)  { l = 1; base = 128;  Cin = 128; bnoff = 256;  OTOT = 256; }
    else if (ob < 640)  { l = 2; base = 384;  Cin = 256; bnoff = 512;  OTOT = 256; }
    else if (ob < 1152) { l = 3; base = 640;  Cin = 256; bnoff = 768;  OTOT = 512; }
    else                { l = 4; base = 1152; Cin = 512; bnoff = 1280; OTOT = 512; }
    const int o = ob - base;
    const float* wo = pk.w[l] + (size_t)o * Cin * 9;

    double s = 0.0;
    for (int k = t; k < Cin * 9; k += 256) s += fabs((double)wo[k]);
    __shared__ double red[256];
    red[t] = s;
    __syncthreads();
    for (int r = 128; r > 0; r >>= 1) {
        if (t < r) red[t] += red[t + r];
        __syncthreads();
    }
    if (t == 0) {
        double alpha = red[0] / (double)(Cin * 9);
        A_all[ob] = alpha * scale_all[bnoff + o];
    }

    const int W64 = Cin / 64;
    u64* wbt = pk.wbt[l];
    for (int e = t; e < 9 * W64; e += 256) {
        int tap = e / W64, word = e % W64;
        u64 bits = 0;
        for (int j = 0; j < 64; ++j) {
            int c = word * 64 + j;
            if (wo[c * 9 + tap] < 0.f) bits |= (1ull << j);
        }
        wbt[((size_t)tap * OTOT + o) * W64 + word] = bits;
    }
}

// ---------------------------------------------------------------------------
// conv0 (f64 exact), lane = pixel -> PADDED bits0 [n][34][34][2].
// ---------------------------------------------------------------------------
__global__ __launch_bounds__(256) void conv0_pack(
        const float* __restrict__ x, const float* __restrict__ w0,
        const double* __restrict__ scale, const double* __restrict__ shift,
        u64* __restrict__ bits0) {
    __shared__ double wlds[128 * 27];
    __shared__ double sc[128], sh[128];
    const int tid = threadIdx.x;
    for (int e = tid; e < 128 * 27; e += 256) wlds[e] = (double)w0[e];
    for (int e = tid; e < 128; e += 256) { sc[e] = scale[e]; sh[e] = shift[e]; }
    __syncthreads();

    const int n = blockIdx.y;
    const int p = blockIdx.x * 256 + tid;
    const int y = p >> 5, xx = p & 31;
    const float* xn = x + (size_t)n * 3 * 32 * 32;

    double win[27];
#pragma unroll
    for (int c = 0; c < 3; ++c)
#pragma unroll
        for (int dy = 0; dy < 3; ++dy)
#pragma unroll
            for (int dx = 0; dx < 3; ++dx) {
                const int yy = y + dy - 1, xs = xx + dx - 1;
                const bool ok = (yy >= 0 && yy < 32 && xs >= 0 && xs < 32);
                win[(c * 3 + dy) * 3 + dx] = ok ? (double)xn[(c * 32 + yy) * 32 + xs] : 0.0;
            }

    u64* op = bits0 + (((size_t)n * 34 + (y + 1)) * 34 + (xx + 1)) * 2;
#pragma unroll
    for (int og = 0; og < 2; ++og) {
        u64 word = 0;
#pragma unroll 2
        for (int j = 0; j < 64; ++j) {
            const int o = og * 64 + j;
            const double* wo = &wlds[o * 27];
            double acc = 0.0;
#pragma unroll
            for (int k = 0; k < 27; ++k) acc = fma(wo[k], win[k], acc);
            const double val = acc * sc[o] + sh[o];
            word |= (u64)(val < 0.0) << j;
        }
        op[og] = word;
    }
}

// ---------------------------------------------------------------------------
// bconv5: padded input (zero ring), NO validity logic in the hot loop —
// per-(tap,oc) body is pure xor + bcnt-accumulate. Exact edge correction via
// per-block pattern table ct[pat][oc] = nv*64*W64 + 2*sum_inv popcount(w).
// v = ct - 2*acc is the same integer as the masked version => bit-identical.
// POOL: 2x2 int max via shfl_xor(1), shfl_xor(W). LAST: htanh f64 -> f32 h5.
// ---------------------------------------------------------------------------
template<int H, int W, int W64, int OTOT, bool POOL, bool LAST, int MINW>
__global__ __launch_bounds__(256, MINW) void bconv5(
        const u64* __restrict__ in_bits, const u64* __restrict__ wbt,
        const double* __restrict__ A, const double* __restrict__ B,
        u32* __restrict__ out_bits, float* __restrict__ h5) {
    const int tid = threadIdx.x;
    const int wave = tid >> 6, lane = tid & 63;
    constexpr int OPW = 32;
    constexpr int WPI = (H * W) / 64;
    constexpr int IPB = (WPI >= 4) ? 1 : (4 / WPI);
    const int img = (IPB == 1) ? blockIdx.z : blockIdx.z * IPB + wave;
    const int wii = (IPB == 1) ? (blockIdx.y * 4 + wave) : 0;
    const int y = wii * (64 / W) + lane / W;
    const int x = lane % W;
    const int obase = blockIdx.x * OPW;

    __shared__ u64 wl[9 * OPW * W64];
    __shared__ u32 ct[16 * OPW];
    __shared__ double Ald[OPW], Bld[OPW];
    {
        for (int e = tid; e < 9 * OPW * W64; e += 256) {
            const int tap = e / (OPW * W64), r = e % (OPW * W64);
            wl[e] = wbt[((size_t)tap * OTOT + obase) * W64 + r];
        }
        for (int e = tid; e < OPW; e += 256) {
            Ald[e] = A[obase + e];
            Bld[e] = B[obase + e];
        }
    }
    __syncthreads();
    // pattern-correction table (16 patterns x 32 oc)
    for (int e = tid; e < 16 * OPW; e += 256) {
        const int pat = e >> 5, oc = e & 31;
        int nv = 0;
        u32 cor = 0;
#pragma unroll
        for (int tap = 0; tap < 9; ++tap) {
            const int dy = tap / 3, dx = tap % 3;
            const bool inv = ((pat & 1) && dy == 0) || ((pat & 2) && dy == 2) ||
                             ((pat & 4) && dx == 0) || ((pat & 8) && dx == 2);
            if (inv) {
#pragma unroll
                for (int k = 0; k < W64; ++k)
                    cor += (u32)__popcll(wl[(tap * OPW + oc) * W64 + k]);
            } else {
                nv++;
            }
        }
        ct[e] = (u32)(nv * 64 * W64) + 2u * cor;
    }
    __syncthreads();

    constexpr int RC = W + 2;
    const u64* ib = in_bits + (size_t)img * (H + 2) * RC * W64;

    int acc[OPW];
#pragma unroll
    for (int i = 0; i < OPW; ++i) acc[i] = 0;

#pragma unroll 1
    for (int dy = 0; dy < 3; ++dy) {
#pragma unroll 1
        for (int dx = 0; dx < 3; ++dx) {
            const u64* q = ib + ((size_t)(y + dy) * RC + (x + dx)) * W64;
            u64 wn[W64];
#pragma unroll
            for (int k = 0; k < W64; ++k) wn[k] = q[k];
            const u64* wt = &wl[(dy * 3 + dx) * OPW * W64];
#pragma unroll
            for (int oc = 0; oc < OPW; ++oc) {
#pragma unroll
                for (int k = 0; k < W64; ++k)
                    acc[oc] += (int)__popcll(wn[k] ^ wt[oc * W64 + k]);
            }
        }
    }

    const int pat = (y == 0 ? 1 : 0) | (y == H - 1 ? 2 : 0) |
                    (x == 0 ? 4 : 0) | (x == W - 1 ? 8 : 0);
    constexpr int Hp = POOL ? H / 2 : H, Wp = POOL ? W / 2 : W;
    const bool writer = (!POOL) || (((lane & 1) == 0) && ((lane & W) == 0));
    const int py = POOL ? (y >> 1) : y, px = POOL ? (x >> 1) : x;

    u32 cur = 0;
#pragma unroll
    for (int oc = 0; oc < OPW; ++oc) {
        int v = (int)ct[(pat << 5) | oc] - 2 * acc[oc];
        if (POOL) {
            int v2 = max(v, __shfl_xor(v, 1, 64));
            v = max(v2, __shfl_xor(v2, W, 64));
        }
        const double t = fma(Ald[oc], (double)v, Bld[oc]);
        if (LAST) {
            const double hcl = fmin(1.0, fmax(-1.0, t));
            if (writer)
                h5[(((size_t)img * OTOT + obase + oc) * Hp + py) * Wp + px] = (float)hcl;
        } else {
            cur |= (u32)(t < 0.0) << oc;
        }
    }
    if (!LAST && writer) {
        // padded output: pixel (py,px) at row py+1, col px+1
        out_bits[(((size_t)img * (Hp + 2) + (py + 1)) * (Wp + 2) + (px + 1)) * (OTOT / 32)
                 + (obase >> 5)] = cur;
    }
}

// ---------------------------------------------------------------------------
// FC (f64 accumulate): out[n,10] = h5[n,8192] @ fcw^T + fcb
// ---------------------------------------------------------------------------
__global__ void fc_kernel(const float* __restrict__ h, const float* __restrict__ fcw,
                          const float* __restrict__ fcb, float* __restrict__ out) {
    const int n = blockIdx.x, t = threadIdx.x;
    double acc[10];
#pragma unroll
    for (int j = 0; j < 10; ++j) acc[j] = 0.0;
    const float* hn = h + (size_t)n * 8192;
    for (int k = t; k < 8192; k += 256) {
        double xv = (double)hn[k];
#pragma unroll
        for (int j = 0; j < 10; ++j) acc[j] += xv * (double)fcw[j * 8192 + k];
    }
    __shared__ double red[10][256];
#pragma unroll
    for (int j = 0; j < 10; ++j) red[j][t] = acc[j];
    __syncthreads();
    for (int r = 128; r > 0; r >>= 1) {
        if (t < r) {
#pragma unroll
            for (int j = 0; j < 10; ++j) red[j][t] += red[j][t + r];
        }
        __syncthreads();
    }
    if (t < 10) out[n * 10 + t] = (float)(red[t][0] + (double)fcb[t]);
}

// ===========================================================================
extern "C" void kernel_launch(void* const* d_in, const int* in_sizes, int n_in,
                              void* d_out, int out_size, void* d_ws, size_t ws_size,
                              hipStream_t stream) {
    const float* X = (const float*)d_in[0];
    BnArgs bn;
    PackArgs pk;
    const float* Wt0 = (const float*)d_in[1];
    for (int i = 0; i < 6; ++i) {
        bn.g[i] = (const float*)d_in[2 + 5 * i];
        bn.b[i] = (const float*)d_in[3 + 5 * i];
        bn.m[i] = (const float*)d_in[4 + 5 * i];
        bn.v[i] = (const float*)d_in[5 + 5 * i];
    }
    for (int i = 0; i < 5; ++i) pk.w[i] = (const float*)d_in[1 + 5 * (i + 1)];
    const float* fcw = (const float*)d_in[31];
    const float* fcb = (const float*)d_in[32];
    float* out = (float*)d_out;

    char* ws = (char*)d_ws;
    size_t off = 0;
    auto alloc = [&](size_t bytes) -> void* {
        void* p = ws + off;
        off = (off + bytes + 255) & ~(size_t)255;
        return p;
    };

    // ---- workspace (~10.7 MB; h5 aliases dead bits0..bits3) ----
    double* scale_all = (double*)alloc(1792 * sizeof(double));
    double* shift_all = (double*)alloc(1792 * sizeof(double));
    double* A_all     = (double*)alloc(1664 * sizeof(double));
    const size_t WBN[5] = {128ull * 9 * 2, 256ull * 9 * 2, 256ull * 9 * 4,
                           512ull * 9 * 4, 512ull * 9 * 8};
    for (int i = 0; i < 5; ++i) pk.wbt[i] = (u64*)alloc(WBN[i] * sizeof(u64));
    // padded bit tensors, contiguous (bits4 first, then bits0..bits3)
    u64* bits4 = (u64*)alloc(256ull * 10 * 10 * 8 * sizeof(u64));
    u64* bits0 = (u64*)alloc(256ull * 34 * 34 * 2 * sizeof(u64));
    u64* bits1 = (u64*)alloc(256ull * 18 * 18 * 2 * sizeof(u64));
    u64* bits2 = (u64*)alloc(256ull * 18 * 18 * 4 * sizeof(u64));
    u64* bits3 = (u64*)alloc(256ull * 10 * 10 * 4 * sizeof(u64));
    const size_t bits_u64 =
        256ull * (10 * 10 * 8 + 34 * 34 * 2 + 18 * 18 * 2 + 18 * 18 * 4 + 10 * 10 * 4);
    // h5 (8.4 MB) aliases bits0..bits3 (7.51 MB) + extra tail
    float* h5 = (float*)bits0;
    {
        const size_t h5_bytes = 256ull * 8192 * sizeof(float);
        const size_t have = (size_t)((char*)(bits3 + 256ull * 10 * 10 * 4) - (char*)bits0);
        if (h5_bytes > have) alloc(h5_bytes - have);
    }

    if (off > ws_size) {
        zero_out<<<dim3((out_size + 255) / 256), dim3(256), 0, stream>>>(out, out_size);
        return;
    }

    const int BOF[6] = {0, 128, 256, 512, 768, 1280};
    const int AOF[5] = {0, 128, 384, 640, 1152};

    // ---- preps ----
    bn_prep_all<<<dim3(7), dim3(256), 0, stream>>>(bn, scale_all, shift_all);
    pack_all<<<dim3(1664), dim3(256), 0, stream>>>(pk, scale_all, A_all);
    zero_u64<<<dim3(2048), dim3(256), 0, stream>>>(bits4, bits_u64);

    // ---- conv0 (padded bits0) ----
    conv0_pack<<<dim3(4, 256), dim3(256), 0, stream>>>(
        X, Wt0, scale_all + BOF[0], shift_all + BOF[0], bits0);

    // ---- binconv chain (padded, correction-table epilogue) ----
    // L1: 128->128, 32x32, pool
    bconv5<32, 32, 2, 128, true, false, 4><<<dim3(4, 4, 256), dim3(256), 0, stream>>>(
        bits0, pk.wbt[0], A_all + AOF[0], shift_all + BOF[1], (u32*)bits1, nullptr);
    // L2: 128->256, 16x16
    bconv5<16, 16, 2, 256, false, false, 4><<<dim3(8, 1, 256), dim3(256), 0, stream>>>(
        bits1, pk.wbt[1], A_all + AOF[1], shift_all + BOF[2], (u32*)bits2, nullptr);
    // L3: 256->256, 16x16, pool
    bconv5<16, 16, 4, 256, true, false, 4><<<dim3(8, 1, 256), dim3(256), 0, stream>>>(
        bits2, pk.wbt[2], A_all + AOF[2], shift_all + BOF[3], (u32*)bits3, nullptr);
    // L4: 256->512, 8x8
    bconv5<8, 8, 4, 512, false, false, 4><<<dim3(16, 1, 64), dim3(256), 0, stream>>>(
        bits3, pk.wbt[3], A_all + AOF[3], shift_all + BOF[4], (u32*)bits4, nullptr);
    // L5: 512->512, 8x8, pool -> h5
    bconv5<8, 8, 8, 512, true, true, 4><<<dim3(16, 1, 64), dim3(256), 0, stream>>>(
        bits4, pk.wbt[4], A_all + AOF[4], shift_all + BOF[5], nullptr, h5);

    // ---- FC ----
    fc_kernel<<<dim3(256), dim3(256), 0, stream>>>(h5, fcw, fcb, out);
}

// Round 14
// 588.220 us; speedup vs baseline: 1.0220x; 1.0220x over previous
//
#include <hip/hip_runtime.h>
#include <cstdint>

#define EPS 1e-5
typedef unsigned long long u64;
typedef unsigned int u32;

struct BnArgs { const float *g[6], *b[6], *m[6], *v[6]; };
struct PackArgs { const float* w[5]; u64* wbt[5]; };

// ---------------------------------------------------------------------------
// Fused BN prep: offsets {0,128,256,512,768,1280}, total 1792.
// ---------------------------------------------------------------------------
__global__ void bn_prep_all(BnArgs p, double* __restrict__ scale_all,
                            double* __restrict__ shift_all) {
    int i = blockIdx.x * 256 + threadIdx.x;
    if (i >= 1792) return;
    int l, base;
    if (i < 128)       { l = 0; base = 0; }
    else if (i < 256)  { l = 1; base = 128; }
    else if (i < 512)  { l = 2; base = 256; }
    else if (i < 768)  { l = 3; base = 512; }
    else if (i < 1280) { l = 4; base = 768; }
    else               { l = 5; base = 1280; }
    const int c = i - base;
    double inv = (double)p.g[l][c] / sqrt((double)p.v[l][c] + EPS);
    scale_all[i] = inv;
    shift_all[i] = (double)p.b[l][c] - (double)p.m[l][c] * inv;
}

__global__ void zero_out(float* __restrict__ out, int n) {
    int i = blockIdx.x * blockDim.x + threadIdx.x;
    if (i < n) out[i] = 0.f;
}

// grid-stride u64 zero (borders of padded bit tensors)
__global__ void zero_u64(u64* __restrict__ p, size_t n) {
    size_t i = (size_t)blockIdx.x * 256 + threadIdx.x;
    const size_t step = (size_t)gridDim.x * 256;
    for (; i < n; i += step) p[i] = 0ull;
}

// ---------------------------------------------------------------------------
// Fused weight pack, tap-major: wbt[(tap*OTOT + o)*W64 + w]. A = alpha*scale.
// Also emits the exact edge-correction table to GLOBAL memory:
//   ct_all[ctoff + pat*OTOT + o] = nv*64*W64 + 2*sum_{invalid taps} popcount(w)
// (the same integers the old per-block build produced => bit-identical).
// ---------------------------------------------------------------------------
__global__ void pack_all(PackArgs pk, const double* __restrict__ scale_all,
                         double* __restrict__ A_all, u32* __restrict__ ct_all) {
    const int ob = blockIdx.x;
    const int t = threadIdx.x;
    int l, base, Cin, bnoff, OTOT, ctoff;
    if (ob < 128)       { l = 0; base = 0;    Cin = 128; bnoff = 128;  OTOT = 128; ctoff = 0; }
    else if (ob < 384)  { l = 1; base = 128;  Cin = 128; bnoff = 256;  OTOT = 256; ctoff = 2048; }
    else if (ob < 640)  { l = 2; base = 384;  Cin = 256; bnoff = 512;  OTOT = 256; ctoff = 6144; }
    else if (ob < 1152) { l = 3; base = 640;  Cin = 256; bnoff = 768;  OTOT = 512; ctoff = 10240; }
    else                { l = 4; base = 1152; Cin = 512; bnoff = 1280; OTOT = 512; ctoff = 18432; }
    const int o = ob - base;
    const float* wo = pk.w[l] + (size_t)o * Cin * 9;

    double s = 0.0;
    for (int k = t; k < Cin * 9; k += 256) s += fabs((double)wo[k]);
    __shared__ double red[256];
    __shared__ u32 stp[9];
    red[t] = s;
    if (t < 9) stp[t] = 0;
    __syncthreads();
    for (int r = 128; r > 0; r >>= 1) {
        if (t < r) red[t] += red[t + r];
        __syncthreads();
    }
    if (t == 0) {
        double alpha = red[0] / (double)(Cin * 9);
        A_all[ob] = alpha * scale_all[bnoff + o];
    }

    const int W64 = Cin / 64;
    u64* wbt = pk.wbt[l];
    for (int e = t; e < 9 * W64; e += 256) {
        int tap = e / W64, word = e % W64;
        u64 bits = 0;
        for (int j = 0; j < 64; ++j) {
            int c = word * 64 + j;
            if (wo[c * 9 + tap] < 0.f) bits |= (1ull << j);
        }
        wbt[((size_t)tap * OTOT + o) * W64 + word] = bits;
        atomicAdd(&stp[tap], (u32)__popcll(bits));
    }
    __syncthreads();

    if (t < 16) {
        const int pat = t;
        int nv = 0;
        u32 cor = 0;
#pragma unroll
        for (int tap = 0; tap < 9; ++tap) {
            const int dy = tap / 3, dx = tap % 3;
            const bool inv = ((pat & 1) && dy == 0) || ((pat & 2) && dy == 2) ||
                             ((pat & 4) && dx == 0) || ((pat & 8) && dx == 2);
            if (inv) cor += stp[tap]; else nv++;
        }
        ct_all[ctoff + pat * OTOT + o] = (u32)(nv * 64 * W64) + 2u * cor;
    }
}

// ---------------------------------------------------------------------------
// conv0 (f64 exact), lane = pixel -> PADDED bits0 [n][34][34][2].
// ---------------------------------------------------------------------------
__global__ __launch_bounds__(256) void conv0_pack(
        const float* __restrict__ x, const float* __restrict__ w0,
        const double* __restrict__ scale, const double* __restrict__ shift,
        u64* __restrict__ bits0) {
    __shared__ double wlds[128 * 27];
    __shared__ double sc[128], sh[128];
    const int tid = threadIdx.x;
    for (int e = tid; e < 128 * 27; e += 256) wlds[e] = (double)w0[e];
    for (int e = tid; e < 128; e += 256) { sc[e] = scale[e]; sh[e] = shift[e]; }
    __syncthreads();

    const int n = blockIdx.y;
    const int p = blockIdx.x * 256 + tid;
    const int y = p >> 5, xx = p & 31;
    const float* xn = x + (size_t)n * 3 * 32 * 32;

    double win[27];
#pragma unroll
    for (int c = 0; c < 3; ++c)
#pragma unroll
        for (int dy = 0; dy < 3; ++dy)
#pragma unroll
            for (int dx = 0; dx < 3; ++dx) {
                const int yy = y + dy - 1, xs = xx + dx - 1;
                const bool ok = (yy >= 0 && yy < 32 && xs >= 0 && xs < 32);
                win[(c * 3 + dy) * 3 + dx] = ok ? (double)xn[(c * 32 + yy) * 32 + xs] : 0.0;
            }

    u64* op = bits0 + (((size_t)n * 34 + (y + 1)) * 34 + (xx + 1)) * 2;
#pragma unroll
    for (int og = 0; og < 2; ++og) {
        u64 word = 0;
#pragma unroll 2
        for (int j = 0; j < 64; ++j) {
            const int o = og * 64 + j;
            const double* wo = &wlds[o * 27];
            double acc = 0.0;
#pragma unroll
            for (int k = 0; k < 27; ++k) acc = fma(wo[k], win[k], acc);
            const double val = acc * sc[o] + sh[o];
            word |= (u64)(val < 0.0) << j;
        }
        op[og] = word;
    }
}

// ---------------------------------------------------------------------------
// bconv6: padded input (zero ring), pure xor+bcnt hot loop. Edge correction
// read from a pre-built global table, staged in LDS with stride 33 so that
// distinct-pat lanes hit distinct banks (conflict-free).
// POOL: 2x2 int max via shfl_xor(1), shfl_xor(W). LAST: htanh f64 -> f32 h5.
// ---------------------------------------------------------------------------
template<int H, int W, int W64, int OTOT, bool POOL, bool LAST, int MINW>
__global__ __launch_bounds__(256, MINW) void bconv6(
        const u64* __restrict__ in_bits, const u64* __restrict__ wbt,
        const double* __restrict__ A, const double* __restrict__ B,
        const u32* __restrict__ ct_all, int ctoff,
        u32* __restrict__ out_bits, float* __restrict__ h5) {
    const int tid = threadIdx.x;
    const int wave = tid >> 6, lane = tid & 63;
    constexpr int OPW = 32;
    constexpr int WPI = (H * W) / 64;
    constexpr int IPB = (WPI >= 4) ? 1 : (4 / WPI);
    const int img = (IPB == 1) ? blockIdx.z : blockIdx.z * IPB + wave;
    const int wii = (IPB == 1) ? (blockIdx.y * 4 + wave) : 0;
    const int y = wii * (64 / W) + lane / W;
    const int x = lane % W;
    const int obase = blockIdx.x * OPW;

    __shared__ u64 wl[9 * OPW * W64];
    __shared__ u32 ctl[16 * 33];
    __shared__ double Ald[OPW], Bld[OPW];
    {
        for (int e = tid; e < 9 * OPW * W64; e += 256) {
            const int tap = e / (OPW * W64), r = e % (OPW * W64);
            wl[e] = wbt[((size_t)tap * OTOT + obase) * W64 + r];
        }
        for (int e = tid; e < 16 * OPW; e += 256) {
            const int pat = e >> 5, oc = e & 31;
            ctl[pat * 33 + oc] = ct_all[ctoff + pat * OTOT + obase + oc];
        }
        for (int e = tid; e < OPW; e += 256) {
            Ald[e] = A[obase + e];
            Bld[e] = B[obase + e];
        }
    }
    __syncthreads();

    constexpr int RC = W + 2;
    const u64* ib = in_bits + (size_t)img * (H + 2) * RC * W64;

    int acc[OPW];
#pragma unroll
    for (int i = 0; i < OPW; ++i) acc[i] = 0;

#pragma unroll 1
    for (int dy = 0; dy < 3; ++dy) {
#pragma unroll 1
        for (int dx = 0; dx < 3; ++dx) {
            const u64* q = ib + ((size_t)(y + dy) * RC + (x + dx)) * W64;
            u64 wn[W64];
#pragma unroll
            for (int k = 0; k < W64; ++k) wn[k] = q[k];
            const u64* wt = &wl[(dy * 3 + dx) * OPW * W64];
#pragma unroll
            for (int oc = 0; oc < OPW; ++oc) {
#pragma unroll
                for (int k = 0; k < W64; ++k)
                    acc[oc] += (int)__popcll(wn[k] ^ wt[oc * W64 + k]);
            }
        }
    }

    const int pat = (y == 0 ? 1 : 0) | (y == H - 1 ? 2 : 0) |
                    (x == 0 ? 4 : 0) | (x == W - 1 ? 8 : 0);
    const int ctbase = pat * 33;
    constexpr int Hp = POOL ? H / 2 : H, Wp = POOL ? W / 2 : W;
    const bool writer = (!POOL) || (((lane & 1) == 0) && ((lane & W) == 0));
    const int py = POOL ? (y >> 1) : y, px = POOL ? (x >> 1) : x;

    u32 cur = 0;
#pragma unroll
    for (int oc = 0; oc < OPW; ++oc) {
        int v = (int)ctl[ctbase + oc] - 2 * acc[oc];
        if (POOL) {
            int v2 = max(v, __shfl_xor(v, 1, 64));
            v = max(v2, __shfl_xor(v2, W, 64));
        }
        const double t = fma(Ald[oc], (double)v, Bld[oc]);
        if (LAST) {
            const double hcl = fmin(1.0, fmax(-1.0, t));
            if (writer)
                h5[(((size_t)img * OTOT + obase + oc) * Hp + py) * Wp + px] = (float)hcl;
        } else {
            cur |= (u32)(t < 0.0) << oc;
        }
    }
    if (!LAST && writer) {
        out_bits[(((size_t)img * (Hp + 2) + (py + 1)) * (Wp + 2) + (px + 1)) * (OTOT / 32)
                 + (obase >> 5)] = cur;
    }
}

// ---------------------------------------------------------------------------
// FC (f64 accumulate): out[n,10] = h5[n,8192] @ fcw^T + fcb
// ---------------------------------------------------------------------------
__global__ void fc_kernel(const float* __restrict__ h, const float* __restrict__ fcw,
                          const float* __restrict__ fcb, float* __restrict__ out) {
    const int n = blockIdx.x, t = threadIdx.x;
    double acc[10];
#pragma unroll
    for (int j = 0; j < 10; ++j) acc[j] = 0.0;
    const float* hn = h + (size_t)n * 8192;
    for (int k = t; k < 8192; k += 256) {
        double xv = (double)hn[k];
#pragma unroll
        for (int j = 0; j < 10; ++j) acc[j] += xv * (double)fcw[j * 8192 + k];
    }
    __shared__ double red[10][256];
#pragma unroll
    for (int j = 0; j < 10; ++j) red[j][t] = acc[j];
    __syncthreads();
    for (int r = 128; r > 0; r >>= 1) {
        if (t < r) {
#pragma unroll
            for (int j = 0; j < 10; ++j) red[j][t] += red[j][t + r];
        }
        __syncthreads();
    }
    if (t < 10) out[n * 10 + t] = (float)(red[t][0] + (double)fcb[t]);
}

// ===========================================================================
extern "C" void kernel_launch(void* const* d_in, const int* in_sizes, int n_in,
                              void* d_out, int out_size, void* d_ws, size_t ws_size,
                              hipStream_t stream) {
    const float* X = (const float*)d_in[0];
    BnArgs bn;
    PackArgs pk;
    const float* Wt0 = (const float*)d_in[1];
    for (int i = 0; i < 6; ++i) {
        bn.g[i] = (const float*)d_in[2 + 5 * i];
        bn.b[i] = (const float*)d_in[3 + 5 * i];
        bn.m[i] = (const float*)d_in[4 + 5 * i];
        bn.v[i] = (const float*)d_in[5 + 5 * i];
    }
    for (int i = 0; i < 5; ++i) pk.w[i] = (const float*)d_in[1 + 5 * (i + 1)];
    const float* fcw = (const float*)d_in[31];
    const float* fcb = (const float*)d_in[32];
    float* out = (float*)d_out;

    char* ws = (char*)d_ws;
    size_t off = 0;
    auto alloc = [&](size_t bytes) -> void* {
        void* p = ws + off;
        off = (off + bytes + 255) & ~(size_t)255;
        return p;
    };

    // ---- workspace (~10.8 MB; h5 aliases dead bits0..bits3) ----
    double* scale_all = (double*)alloc(1792 * sizeof(double));
    double* shift_all = (double*)alloc(1792 * sizeof(double));
    double* A_all     = (double*)alloc(1664 * sizeof(double));
    u32* ct_all       = (u32*)alloc(26624 * sizeof(u32));
    const size_t WBN[5] = {128ull * 9 * 2, 256ull * 9 * 2, 256ull * 9 * 4,
                           512ull * 9 * 4, 512ull * 9 * 8};
    for (int i = 0; i < 5; ++i) pk.wbt[i] = (u64*)alloc(WBN[i] * sizeof(u64));
    // padded bit tensors, contiguous (bits4 first, then bits0..bits3)
    u64* bits4 = (u64*)alloc(256ull * 10 * 10 * 8 * sizeof(u64));
    u64* bits0 = (u64*)alloc(256ull * 34 * 34 * 2 * sizeof(u64));
    u64* bits1 = (u64*)alloc(256ull * 18 * 18 * 2 * sizeof(u64));
    u64* bits2 = (u64*)alloc(256ull * 18 * 18 * 4 * sizeof(u64));
    u64* bits3 = (u64*)alloc(256ull * 10 * 10 * 4 * sizeof(u64));
    const size_t bits_u64 =
        256ull * (10 * 10 * 8 + 34 * 34 * 2 + 18 * 18 * 2 + 18 * 18 * 4 + 10 * 10 * 4);
    // h5 (8.4 MB) aliases bits0..bits3 (7.51 MB) + extra tail
    float* h5 = (float*)bits0;
    {
        const size_t h5_bytes = 256ull * 8192 * sizeof(float);
        const size_t have = (size_t)((char*)(bits3 + 256ull * 10 * 10 * 4) - (char*)bits0);
        if (h5_bytes > have) alloc(h5_bytes - have);
    }

    if (off > ws_size) {
        zero_out<<<dim3((out_size + 255) / 256), dim3(256), 0, stream>>>(out, out_size);
        return;
    }

    const int BOF[6] = {0, 128, 256, 512, 768, 1280};
    const int AOF[5] = {0, 128, 384, 640, 1152};
    const int CTO[5] = {0, 2048, 6144, 10240, 18432};

    // ---- preps ----
    bn_prep_all<<<dim3(7), dim3(256), 0, stream>>>(bn, scale_all, shift_all);
    pack_all<<<dim3(1664), dim3(256), 0, stream>>>(pk, scale_all, A_all, ct_all);
    zero_u64<<<dim3(2048), dim3(256), 0, stream>>>(bits4, bits_u64);

    // ---- conv0 (padded bits0) ----
    conv0_pack<<<dim3(4, 256), dim3(256), 0, stream>>>(
        X, Wt0, scale_all + BOF[0], shift_all + BOF[0], bits0);

    // ---- binconv chain (padded, global correction table) ----
    // L1: 128->128, 32x32, pool
    bconv6<32, 32, 2, 128, true, false, 4><<<dim3(4, 4, 256), dim3(256), 0, stream>>>(
        bits0, pk.wbt[0], A_all + AOF[0], shift_all + BOF[1], ct_all, CTO[0],
        (u32*)bits1, nullptr);
    // L2: 128->256, 16x16
    bconv6<16, 16, 2, 256, false, false, 4><<<dim3(8, 1, 256), dim3(256), 0, stream>>>(
        bits1, pk.wbt[1], A_all + AOF[1], shift_all + BOF[2], ct_all, CTO[1],
        (u32*)bits2, nullptr);
    // L3: 256->256, 16x16, pool
    bconv6<16, 16, 4, 256, true, false, 4><<<dim3(8, 1, 256), dim3(256), 0, stream>>>(
        bits2, pk.wbt[2], A_all + AOF[2], shift_all + BOF[3], ct_all, CTO[2],
        (u32*)bits3, nullptr);
    // L4: 256->512, 8x8
    bconv6<8, 8, 4, 512, false, false, 4><<<dim3(16, 1, 64), dim3(256), 0, stream>>>(
        bits3, pk.wbt[3], A_all + AOF[3], shift_all + BOF[4], ct_all, CTO[3],
        (u32*)bits4, nullptr);
    // L5: 512->512, 8x8, pool -> h5
    bconv6<8, 8, 8, 512, true, true, 4><<<dim3(16, 1, 64), dim3(256), 0, stream>>>(
        bits4, pk.wbt[4], A_all + AOF[4], shift_all + BOF[5], ct_all, CTO[4],
        nullptr, h5);

    // ---- FC ----
    fc_kernel<<<dim3(256), dim3(256), 0, stream>>>(h5, fcw, fcb, out);
}